// Round 9
// baseline (101.268 us; speedup 1.0000x reference)
//
#include <hip/hip_runtime.h>

#define NN 100
#define CC 32
#define HEE 32
#define FF 64
#define TILE 10

typedef float f32x4 __attribute__((ext_vector_type(4)));
typedef __bf16 bf16x8 __attribute__((ext_vector_type(8)));
#define MFMA16 __builtin_amdgcn_mfma_f32_16x16x32_bf16

union FragU {
  unsigned short s[8];
  bf16x8 v;
  float4 f4;
};

// round-to-nearest-even bf16 split: v ~= hi + lo
static __device__ __forceinline__ void split2(float v, unsigned short& h, unsigned short& l) {
  union { float f; unsigned u; } c; c.f = v;
  unsigned r = c.u + 0x7FFF + ((c.u >> 16) & 1);
  unsigned short hs = (unsigned short)(r >> 16);
  union { unsigned u; float f; } hb; hb.u = ((unsigned)hs) << 16;
  float rem = v - hb.f;
  union { float f; unsigned u; } c2; c2.f = rem;
  unsigned r2 = c2.u + 0x7FFF + ((c2.u >> 16) & 1);
  h = hs; l = (unsigned short)(r2 >> 16);
}

// ---------------- k_combo: [0,3200) hidden; [3200,3208) fmtW; [3208,3720) preP ----------------
__global__ __launch_bounds__(256) void k_combo(
    const float* __restrict__ x, const float* __restrict__ A,
    const float* __restrict__ ew1, const float* __restrict__ eb1,
    const float* __restrict__ gw0, const float* __restrict__ gw1,
    const float* __restrict__ gw2,
    float* __restrict__ hi, float* __restrict__ hj, float* __restrict__ d0,
    float* __restrict__ Wimg, float* __restrict__ Pimg) {
  int blk = blockIdx.x;
  int t = threadIdx.x;

  if (blk < 3200) {
    // ---- hidden: 4 waves, wave handles one (b,n) row ----
    __shared__ float xr[4][CC];
    int wid = t >> 6, lane = t & 63;
    int bn = blk * 4 + wid;
    if (lane < CC) xr[wid][lane] = x[bn * CC + lane];

    const float* arow = A + (size_t)bn * NN;
    float s = arow[lane] + (lane < NN - 64 ? arow[lane + 64] : 0.f);
#pragma unroll
    for (int off = 32; off > 0; off >>= 1) s += __shfl_down(s, off);
    if (lane == 0) d0[bn] = 1.0f / sqrtf(s + 1.0f + 1e-5f);
    __syncthreads();

    int k = lane & 31;
    const float* w = ew1 + (lane < 32 ? 0 : CC * HEE) + k;
    float acc = (lane < 32) ? eb1[k] : 0.f;
#pragma unroll
    for (int c = 0; c < CC; ++c) acc += xr[wid][c] * w[c * HEE];
    if (lane < 32) hi[bn * HEE + k] = acc;
    else           hj[bn * HEE + k] = acc;
    return;
  }

  if (blk < 3208) {
    // ---- fmtW: W fragment images for gw1 (wsel 0), gw2 (wsel 1) ----
    int gid = (blk - 3200) * 256 + t;
    int lane = gid & 63;
    int frag = gid >> 6;  // 0..31
    int wsel = frag >> 4;
    int rr = frag & 15;
    int kt2 = rr >> 3, nt2 = rr & 7;
    int n = nt2 * 16 + (lane & 15);
    int rel = n >> 6, f = n & 63;
    int kb = kt2 * 32 + (lane >> 4) * 8;
    const float* W = wsel ? gw2 : gw1;
    FragU hh, ll;
#pragma unroll
    for (int e = 0; e < 8; ++e) {
      float v = W[(size_t)(rel * 64 + kb + e) * 64 + f];
      split2(v, hh.s[e], ll.s[e]);
    }
    char* dst = (char*)Wimg + (size_t)frag * 2048 + lane * 16;
    *(float4*)dst = hh.f4;
    *(float4*)(dst + 1024) = ll.f4;
    return;
  }

  // ---- preP: P0 = x@gw0 emitted as P-image ----
  {
    int idx = blk - 3208;
    int b = idx & 127;
    int q = idx >> 7;
    int wid = t >> 6;
    int lane = t & 63;
    int rg = wid * 4 + q;
    int row0 = rg * 8;
    if (row0 >= NN) return;

    int rowc[8];
#pragma unroll
    for (int r = 0; r < 8; ++r) rowc[r] = min(row0 + r, NN - 1);

    float acc0[8], acc1[8];
#pragma unroll
    for (int r = 0; r < 8; ++r) { acc0[r] = 0.f; acc1[r] = 0.f; }

    for (int c4 = 0; c4 < CC / 4; ++c4) {
      int c = c4 * 4;
      float w00 = gw0[(size_t)c * 64 + lane];
      float w01 = gw0[(size_t)(c + 1) * 64 + lane];
      float w02 = gw0[(size_t)(c + 2) * 64 + lane];
      float w03 = gw0[(size_t)(c + 3) * 64 + lane];
      float w10 = gw0[(size_t)(CC + c) * 64 + lane];
      float w11 = gw0[(size_t)(CC + c + 1) * 64 + lane];
      float w12 = gw0[(size_t)(CC + c + 2) * 64 + lane];
      float w13 = gw0[(size_t)(CC + c + 3) * 64 + lane];
#pragma unroll
      for (int r = 0; r < 8; ++r) {
        float4 a4 = *(const float4*)(x + ((size_t)b * NN + rowc[r]) * CC + c);
        acc0[r] += a4.x * w00 + a4.y * w01 + a4.z * w02 + a4.w * w03;
        acc1[r] += a4.x * w10 + a4.y * w11 + a4.z * w12 + a4.w * w13;
      }
    }
#pragma unroll
    for (int r = 0; r < 8; ++r) {
      if (row0 + r >= NN) { acc0[r] = 0.f; acc1[r] = 0.f; }
    }
    int o_t = (row0 & 31) >> 3;
    int lane_t = o_t * 16 + (lane & 15);
    int nt_t = lane >> 4;
    FragU h0, l0, h1, l1;
#pragma unroll
    for (int r = 0; r < 8; ++r) {
      split2(acc0[r], h0.s[r], l0.s[r]);
      split2(acc1[r], h1.s[r], l1.s[r]);
    }
    char* base = (char*)Pimg + (size_t)b * 65536;
    int kt0 = row0 >> 5;
    char* dp0 = base + (size_t)(kt0 * 4 + nt_t) * 2048 + lane_t * 16;
    *(float4*)dp0 = h0.f4;
    *(float4*)(dp0 + 1024) = l0.f4;
    char* dp1 = base + (size_t)((4 + kt0) * 4 + nt_t) * 2048 + lane_t * 16;
    *(float4*)dp1 = h1.f4;
    *(float4*)(dp1 + 1024) = l1.f4;
  }
}

// ---------------- k_edge: Ahat1 = A_pred + I, d1 (i-side register cached) ----------------
// grid B*10, 320 threads. thread: r = t>>5 (row), jl = t&31; j = jl + 32*s.
__global__ __launch_bounds__(320) void k_edge(
    const float* __restrict__ hi, const float* __restrict__ hj,
    const float* __restrict__ ew2, const float* __restrict__ eb2,
    const float* __restrict__ mask,
    float* __restrict__ Ahat1, float* __restrict__ d1) {
  __shared__ __align__(16) float shi[NN * HEE];
  __shared__ __align__(16) float shj[NN * HEE];
  __shared__ __align__(16) float sw2[HEE];
  __shared__ float sm[NN];
  __shared__ float sA[TILE][NN + 4];
  int t = threadIdx.x;
  int b = blockIdx.x / 10;
  int i0 = (blockIdx.x % 10) * TILE;

  const float4* hi4 = (const float4*)(hi + (size_t)b * NN * HEE);
  const float4* hj4 = (const float4*)(hj + (size_t)b * NN * HEE);
  float4* shi4 = (float4*)shi;
  float4* shj4 = (float4*)shj;
  for (int v = t; v < NN * 8; v += 320) {
    int j = v >> 3, k4 = v & 7;
    int sw = (j << 3) | (k4 ^ (j & 7));
    shi4[sw] = hi4[v];
    shj4[sw] = hj4[v];
  }
  if (t < HEE) sw2[t] = ew2[t];
  if (t < NN) sm[t] = mask[b * NN + t];
  __syncthreads();

  int r = t >> 5, jl = t & 31;
  int i = i0 + r;
  float4* sw24 = (float4*)sw2;

  // i-side register cache (wave-half uniform addresses -> broadcast reads)
  float4 hii[8], hji[8];
#pragma unroll
  for (int k4 = 0; k4 < 8; ++k4) {
    int sw = (i << 3) | (k4 ^ (i & 7));
    hii[k4] = shi4[sw];
    hji[k4] = shj4[sw];
  }
  float e2 = eb2[0];
  float mi = sm[i];
  float* Ar = Ahat1 + ((size_t)b * NN + i) * NN;

#pragma unroll
  for (int s = 0; s < 4; ++s) {
    int j = jl + 32 * s;
    if (j < NN) {
      float a1 = 0.f, a2 = 0.f;
#pragma unroll
      for (int k4 = 0; k4 < 8; ++k4) {
        int sw = (j << 3) | (k4 ^ (j & 7));
        float4 hjjK = shj4[sw];
        float4 hijK = shi4[sw];
        float4 w4 = sw24[k4];
        float4 hiiK = hii[k4], hjiK = hji[k4];
        a1 += fmaxf(hiiK.x + hjjK.x, 0.f) * w4.x;
        a2 += fmaxf(hijK.x + hjiK.x, 0.f) * w4.x;
        a1 += fmaxf(hiiK.y + hjjK.y, 0.f) * w4.y;
        a2 += fmaxf(hijK.y + hjiK.y, 0.f) * w4.y;
        a1 += fmaxf(hiiK.z + hjjK.z, 0.f) * w4.z;
        a2 += fmaxf(hijK.z + hjiK.z, 0.f) * w4.z;
        a1 += fmaxf(hiiK.w + hjjK.w, 0.f) * w4.w;
        a2 += fmaxf(hijK.w + hjiK.w, 0.f) * w4.w;
      }
      float val = (j == i) ? 1.0f
                           : expf(0.5f * (a1 + a2) + e2) * mi * sm[j];
      sA[r][j] = val;
      Ar[j] = val;
    }
  }
  __syncthreads();

  // d1: per-row sum, width-32 shuffle reduce
  float s2 = sA[r][jl] + sA[r][jl + 32] + sA[r][jl + 64] +
             (jl < NN - 96 ? sA[r][jl + 96] : 0.f);
#pragma unroll
  for (int off = 16; off > 0; off >>= 1) s2 += __shfl_down(s2, off, 32);
  if (jl == 0) d1[b * NN + i] = 1.0f / sqrtf(s2 + 1e-5f);
}

// ---------------- k_fmtL: L fragment image (A-operand), split bf16 ----------------
__global__ __launch_bounds__(256) void k_fmtL(
    const float* __restrict__ A, const float* __restrict__ Ahat1,
    const float* __restrict__ d0, const float* __restrict__ d1,
    float* __restrict__ Limg) {
  int gid = blockIdx.x * 256 + threadIdx.x;
  int lane = gid & 63;
  int frag = gid >> 6;           // 0 .. 128*56-1
  int b = frag / 56;
  int r = frag % 56;
  int mt = r >> 3, kt = r & 7;
  int m = mt * 16 + (lane & 15);
  int o = lane >> 4;
  int rel = kt >> 2;
  int jb = (kt & 3) * 32 + o * 8;

  float v[8];
  if (m < NN) {
    if (rel == 0) {
      float di = d0[b * NN + m];
      const float* Ar = A + ((size_t)b * NN + m) * NN;
#pragma unroll
      for (int e = 0; e < 8; ++e) {
        int j = jb + e;
        v[e] = (j < NN) ? di * (Ar[j] + (j == m ? 1.f : 0.f)) * d0[b * NN + j] : 0.f;
      }
    } else {
      float di = d1[b * NN + m];
      const float* Ar = Ahat1 + ((size_t)b * NN + m) * NN;
#pragma unroll
      for (int e = 0; e < 8; ++e) {
        int j = jb + e;
        v[e] = (j < NN) ? di * Ar[j] * d1[b * NN + j] : 0.f;
      }
    }
  } else {
#pragma unroll
    for (int e = 0; e < 8; ++e) v[e] = 0.f;
  }
  FragU hh, ll;
#pragma unroll
  for (int e = 0; e < 8; ++e) split2(v[e], hh.s[e], ll.s[e]);
  char* dst = (char*)Limg + (size_t)frag * 2048 + lane * 16;
  *(float4*)dst = hh.f4;
  *(float4*)(dst + 1024) = ll.f4;
}

// ---------------- k_layer: fused gmm1+gmm2 ----------------
// grid B*7 (b, mt), 256 threads; wave w -> nt = w.
// gmm1: acc = L[mt,:] @ P[:, nt] (24 MFMA); relu/bias/mask.
// !LAST: out tile -> swizzled LDS; epilogue: P_next frags for nt2 = {2w, 2w+1} (12 MFMA).
// LAST: per-f max over tile rows -> pooled[b][mt][f].
template <int LAST>
__global__ __launch_bounds__(256) void k_layer(
    const float* __restrict__ Limg, const float* __restrict__ Pimg,
    const float* __restrict__ bias, const float* __restrict__ mask,
    const char* __restrict__ Wimg, float* __restrict__ Pout,
    float* __restrict__ pooled) {
  __shared__ __align__(16) float sO[16 * 64];
  int t = threadIdx.x;
  int b = blockIdx.x / 7;
  int mt = blockIdx.x % 7;
  int w = t >> 6;
  int lane = t & 63;
  int nt = w;

  const char* Lb = (const char*)Limg + (size_t)b * 114688;
  const char* Pb = (const char*)Pimg + (size_t)b * 65536;

  f32x4 acc = {0.f, 0.f, 0.f, 0.f};
#pragma unroll
  for (int kt = 0; kt < 8; ++kt) {
    FragU bh, bl, ah, al;
    const char* pp = Pb + (size_t)(kt * 4 + nt) * 2048 + lane * 16;
    bh.f4 = *(const float4*)pp;
    bl.f4 = *(const float4*)(pp + 1024);
    const char* lp = Lb + (size_t)(mt * 8 + kt) * 2048 + lane * 16;
    ah.f4 = *(const float4*)lp;
    al.f4 = *(const float4*)(lp + 1024);
    acc = MFMA16(ah.v, bh.v, acc, 0, 0, 0);
    acc = MFMA16(al.v, bh.v, acc, 0, 0, 0);
    acc = MFMA16(ah.v, bl.v, acc, 0, 0, 0);
  }

  int f = nt * 16 + (lane & 15);
  float biasf = bias[f];
  const float* mb = mask + b * NN;
  int rbase = (lane >> 4) * 4;
  float vv[4];
#pragma unroll
  for (int reg = 0; reg < 4; ++reg) {
    int gi = mt * 16 + rbase + reg;
    vv[reg] = (gi < NN) ? fmaxf((acc[reg] + biasf) * mb[gi], 0.f) : 0.f;
  }

  if (LAST) {
    float mx = fmaxf(fmaxf(vv[0], vv[1]), fmaxf(vv[2], vv[3]));
    mx = fmaxf(mx, __shfl_xor(mx, 16));
    mx = fmaxf(mx, __shfl_xor(mx, 32));
    if (lane < 16) pooled[((size_t)b * 7 + mt) * 64 + w * 16 + lane] = mx;
    return;
  }

  // store out tile to LDS with chunk-XOR swizzle: word = row*64 + ((c^(row&7))<<3) + e
#pragma unroll
  for (int reg = 0; reg < 4; ++reg) {
    int lr2 = rbase + reg;
    sO[lr2 * 64 + ((((f >> 3) ^ (lr2 & 7)) << 3) | (f & 7))] = vv[reg];
  }
  __syncthreads();

  int ml = lane & 15, o = lane >> 4;
  f32x4 accE0 = {0.f, 0.f, 0.f, 0.f};
  f32x4 accE1 = {0.f, 0.f, 0.f, 0.f};
#pragma unroll
  for (int kt2 = 0; kt2 < 2; ++kt2) {
    int c = kt2 * 4 + o;
    int cp = c ^ (ml & 7);
    const float* op = &sO[ml * 64 + (cp << 3)];
    float4 v0 = *(const float4*)op;
    float4 v1 = *(const float4*)(op + 4);
    float ve[8] = {v0.x, v0.y, v0.z, v0.w, v1.x, v1.y, v1.z, v1.w};
    FragU ah, al;
#pragma unroll
    for (int e = 0; e < 8; ++e) split2(ve[e], ah.s[e], al.s[e]);
    const char* wp0 = Wimg + (size_t)(kt2 * 8 + 2 * w) * 2048 + lane * 16;
    const char* wp1 = Wimg + (size_t)(kt2 * 8 + 2 * w + 1) * 2048 + lane * 16;
    FragU b0h, b0l, b1h, b1l;
    b0h.f4 = *(const float4*)wp0;
    b0l.f4 = *(const float4*)(wp0 + 1024);
    b1h.f4 = *(const float4*)wp1;
    b1l.f4 = *(const float4*)(wp1 + 1024);
    accE0 = MFMA16(ah.v, b0h.v, accE0, 0, 0, 0);
    accE0 = MFMA16(al.v, b0h.v, accE0, 0, 0, 0);
    accE0 = MFMA16(ah.v, b0l.v, accE0, 0, 0, 0);
    accE1 = MFMA16(ah.v, b1h.v, accE1, 0, 0, 0);
    accE1 = MFMA16(al.v, b1h.v, accE1, 0, 0, 0);
    accE1 = MFMA16(ah.v, b1l.v, accE1, 0, 0, 0);
  }

  // write P-image frags for nt2 = 2w (accE0) and 2w+1 (accE1)
  char* Pob = (char*)Pout + (size_t)b * 65536;
  int i0r = mt * 16 + o * 4;
#pragma unroll
  for (int half = 0; half < 2; ++half) {
    f32x4 aE = half ? accE1 : accE0;
    int nt2 = 2 * w + half;
    int np = nt2 * 16 + ml;
    int rel = np >> 6;
    int fp = np & 63;
    int kk = rel * 128 + i0r;
    int kt_ = kk >> 5;
    int o_t = (kk & 31) >> 3;
    int e0 = i0r & 7;  // 0 or 4
    unsigned short hs[4], ls[4];
#pragma unroll
    for (int reg = 0; reg < 4; ++reg) split2(aE[reg], hs[reg], ls[reg]);
    ushort4 hv = {hs[0], hs[1], hs[2], hs[3]};
    ushort4 lv = {ls[0], ls[1], ls[2], ls[3]};
    char* dst = Pob + (size_t)(kt_ * 4 + (fp >> 4)) * 2048 + (o_t * 16 + (fp & 15)) * 16 + e0 * 2;
    *(ushort4*)dst = hv;
    *(ushort4*)(dst + 1024) = lv;
  }
}

// ---------------- k_final: max over 7 mt partials + classifier ----------------
__global__ __launch_bounds__(64) void k_final(
    const float* __restrict__ pooled, const float* __restrict__ fw,
    const float* __restrict__ fb, float* __restrict__ out) {
  int b = blockIdx.x;
  int t = threadIdx.x;
  __shared__ float sp[FF];
  float m = -3.402823466e38f;
  const float* pb = pooled + (size_t)b * 7 * 64;
#pragma unroll
  for (int rg = 0; rg < 7; ++rg) m = fmaxf(m, pb[rg * 64 + t]);
  sp[t] = m;
  __syncthreads();
  if (t < 16) {
    float acc = fb[t];
#pragma unroll
    for (int f = 0; f < FF; ++f) acc += sp[f] * fw[f * 16 + t];
    out[b * 16 + t] = acc;
  }
}

extern "C" void kernel_launch(void* const* d_in, const int* in_sizes, int n_in,
                              void* d_out, int out_size, void* d_ws, size_t ws_size,
                              hipStream_t stream) {
  const float* x    = (const float*)d_in[0];
  const float* A    = (const float*)d_in[1];
  const float* mask = (const float*)d_in[2];
  const float* ew1  = (const float*)d_in[3];
  const float* eb1  = (const float*)d_in[4];
  const float* ew2  = (const float*)d_in[5];
  const float* eb2  = (const float*)d_in[6];
  const float* gw0  = (const float*)d_in[7];
  const float* gb0  = (const float*)d_in[8];
  const float* gw1  = (const float*)d_in[9];
  const float* gb1  = (const float*)d_in[10];
  const float* gw2  = (const float*)d_in[11];
  const float* gb2  = (const float*)d_in[12];
  const float* fw   = (const float*)d_in[13];
  const float* fb   = (const float*)d_in[14];
  float* out = (float*)d_out;
  float* ws = (float*)d_ws;

  const int B = 128;
  float* hi   = ws;                      // 409600
  float* hj   = hi + 409600;             // 409600
  float* Ah1  = hj + 409600;             // 1280000
  float* d0   = Ah1 + 1280000;           // 12800
  float* d1   = d0 + 12800;              // 12800
  float* Limg = d1 + 12800;              // 3670016 f (128*56*2048 B)
  float* PA   = Limg + 3670016;          // 2097152 f (128*32*2048 B)
  float* PB   = PA + 2097152;            // 2097152 f
  float* Wimg = PB + 2097152;            // 16384 f (32*2048 B)
  float* pooled = Wimg + 16384;          // 128*7*64 = 57344

  k_combo<<<3720, 256, 0, stream>>>(x, A, ew1, eb1, gw0, gw1, gw2,
                                    hi, hj, d0, Wimg, PA);
  k_edge<<<B * 10, 320, 0, stream>>>(hi, hj, ew2, eb2, mask, Ah1, d1);
  k_fmtL<<<1792, 256, 0, stream>>>(A, Ah1, d0, d1, Limg);

  k_layer<0><<<B * 7, 256, 0, stream>>>(Limg, PA, gb0, mask, (const char*)Wimg, PB, pooled);
  k_layer<0><<<B * 7, 256, 0, stream>>>(Limg, PB, gb1, mask, (const char*)Wimg + 32768, PA, pooled);
  k_layer<1><<<B * 7, 256, 0, stream>>>(Limg, PA, gb2, mask, (const char*)Wimg, PB, pooled);

  k_final<<<B, 64, 0, stream>>>(pooled, fw, fb, out);
}